// Round 1
// baseline (12420.525 us; speedup 1.0000x reference)
//
#include <hip/hip_runtime.h>

#define TT 512
#define BB 64
#define EMB 512
#define HID 1024
#define K4 1536
#define NBLK 128
#define THREADS 512

typedef __bf16 bf16x8 __attribute__((ext_vector_type(8)));
typedef float f32x4 __attribute__((ext_vector_type(4)));

__device__ __forceinline__ unsigned short f2bf(float f) {
    union { float f; unsigned u; } v; v.f = f;
    unsigned u = v.u;
    unsigned r = u + 0x7FFFu + ((u >> 16) & 1u);
    return (unsigned short)(r >> 16);
}

__global__ void zero_kernel(unsigned* p, int n) {
    int i = blockIdx.x * 256 + threadIdx.x;
    if (i < n) p[i] = 0u;
}

// Gather embedding rows, cast to bf16: xe_all[t][b][0:512]
__global__ void xe_kernel(const int* __restrict__ x, const float* __restrict__ emb,
                          unsigned short* __restrict__ xe_all) {
    int rowid = blockIdx.x;            // t*64 + b
    int t = rowid >> 6, b = rowid & 63;
    int idx = x[b * TT + t];
    float4 v = ((const float4*)(emb + (long)idx * EMB))[threadIdx.x];
    ushort4 o;
    o.x = f2bf(v.x); o.y = f2bf(v.y); o.z = f2bf(v.z); o.w = f2bf(v.w);
    ((ushort4*)(xe_all + (long)rowid * EMB))[threadIdx.x] = o;
}

// Wpack[n][k] bf16, n in [0,4096): gate=n>>10, col=n&1023; k<512 from Wx_gate, else Wh_gate.
__global__ void wpack_kernel(const float* __restrict__ Wxi, const float* __restrict__ Whi,
                             const float* __restrict__ Wxf, const float* __restrict__ Whf,
                             const float* __restrict__ Wxc, const float* __restrict__ Whc,
                             const float* __restrict__ Wxo, const float* __restrict__ Who,
                             unsigned short* __restrict__ Wpack) {
    const float* Wx[4] = {Wxi, Wxf, Wxc, Wxo};
    const float* Wh[4] = {Whi, Whf, Whc, Who};
    int n0 = (blockIdx.x & 15) << 8;       // 0..3840 step 256
    int k0 = (blockIdx.x >> 4) << 3;       // 0..1528 step 8
    int g = n0 >> 10, col0 = n0 & 1023;
    const float* base = (k0 < 512) ? (Wx[g] + (long)k0 * HID + col0)
                                   : (Wh[g] + (long)(k0 - 512) * HID + col0);
    int tid = threadIdx.x;
    union { unsigned short s[8]; uint4 v; } out;
#pragma unroll
    for (int i = 0; i < 8; ++i) out.s[i] = f2bf(base[(long)i * HID + tid]);
    *(uint4*)(Wpack + (long)(n0 + tid) * K4 + k0) = out.v;
}

__launch_bounds__(THREADS, 1)
__global__ void lstm_kernel(const unsigned short* __restrict__ xe_all,
                            const unsigned short* __restrict__ Wpack,
                            unsigned short* __restrict__ hbuf,   // [2][64][1024] bf16
                            float* __restrict__ hfinal,          // [64][1024] f32
                            unsigned* __restrict__ arrive,       // [512]
                            const float* __restrict__ bi_p, const float* __restrict__ bf_p,
                            const float* __restrict__ bc_p, const float* __restrict__ bo_p) {
    __shared__ unsigned short Wlds[32 * 1544];      // [c][k], pad 8 per row
    __shared__ float partials[4][64][34];           // [kslice][m][c]

    const int tid = threadIdx.x;
    const int wave = tid >> 6, lane = tid & 63;
    const int quad = lane >> 4, r16 = lane & 15;
    const int mt2 = wave & 1;          // m-half: rows mt2*32..+32
    const int ks4 = wave >> 1;         // k-slice: [ks4*384, +384)
    const int kbase = ks4 * 384;
    const int bid = blockIdx.x;
    const int j0 = bid * 8;            // hidden slice [j0, j0+8)

    // ---- load W slice (32 gate-cols x 1536) into LDS, once ----
#pragma unroll
    for (int i = 0; i < 12; ++i) {
        int gidx = tid + i * THREADS;          // 0..6143
        int c = gidx / 192, q = gidx % 192;
        int n = ((c >> 3) << 10) + j0 + (c & 7);
        *(uint4*)(&Wlds[c * 1544 + q * 8]) = *(const uint4*)(Wpack + (long)n * K4 + q * 8);
    }
    // per-thread cell state + biases (thread -> (b,jj))
    const int b_ = tid >> 3, jj = tid & 7;
    float rb0 = bi_p[j0 + jj], rb1 = bf_p[j0 + jj], rb2 = bc_p[j0 + jj], rb3 = bo_p[j0 + jj];
    float c_state = 0.f;
    __syncthreads();

    const f32x4 zf = {0.f, 0.f, 0.f, 0.f};

    for (int t = 0; t < TT; ++t) {
        if (t > 0 && ks4 > 0) {   // waves touching h wait for all blocks' step t-1
            while (__hip_atomic_load(&arrive[t - 1], __ATOMIC_RELAXED, __HIP_MEMORY_SCOPE_AGENT) < NBLK)
                __builtin_amdgcn_s_sleep(1);
            __builtin_amdgcn_fence(__ATOMIC_ACQUIRE, "agent");
        }
        const unsigned short* xe_t = xe_all + (long)t * (BB * EMB);
        const unsigned short* hb = hbuf + (t & 1) * (BB * HID);

        f32x4 acc[2][2];
        acc[0][0] = zf; acc[0][1] = zf; acc[1][0] = zf; acc[1][1] = zf;

        auto load_frags = [&](int ks, bf16x8* a, bf16x8* b) {
            int k = kbase + ks * 32;
            int koff = k + quad * 8;               // never straddles the 512 boundary
            bool inxe = koff < 512;
            const unsigned short* base = inxe ? (xe_t + koff) : (hb + (koff - 512));
            int stride = inxe ? EMB : HID;
#pragma unroll
            for (int mi = 0; mi < 2; ++mi) {
                int row = (mt2 * 2 + mi) * 16 + r16;
                a[mi] = *(const bf16x8*)(base + (long)row * stride);
            }
#pragma unroll
            for (int ni = 0; ni < 2; ++ni)
                b[ni] = *(const bf16x8*)(&Wlds[(ni * 16 + r16) * 1544 + koff - quad * 8 + quad * 8]);
            // note: B address uses k + quad*8 == koff
        };

        bf16x8 aC[2], bC[2], aN[2], bN[2];
        load_frags(0, aC, bC);
#pragma unroll
        for (int ks = 0; ks < 12; ++ks) {
            if (ks < 11) load_frags(ks + 1, aN, bN);
#pragma unroll
            for (int mi = 0; mi < 2; ++mi)
#pragma unroll
                for (int ni = 0; ni < 2; ++ni)
                    acc[mi][ni] = __builtin_amdgcn_mfma_f32_16x16x32_bf16(aC[mi], bC[ni], acc[mi][ni], 0, 0, 0);
            aC[0] = aN[0]; aC[1] = aN[1]; bC[0] = bN[0]; bC[1] = bN[1];
        }

        // write partials (C layout: col=lane&15, row=(lane>>4)*4+reg)
#pragma unroll
        for (int mi = 0; mi < 2; ++mi)
#pragma unroll
            for (int ni = 0; ni < 2; ++ni)
#pragma unroll
                for (int rr = 0; rr < 4; ++rr)
                    partials[ks4][(mt2 * 2 + mi) * 16 + quad * 4 + rr][ni * 16 + r16] = acc[mi][ni][rr];
        __syncthreads();

        // elementwise: thread -> (b_, jj)
        float gi = 0.f, gf = 0.f, gc = 0.f, go = 0.f;
#pragma unroll
        for (int w = 0; w < 4; ++w) {
            gi += partials[w][b_][jj];
            gf += partials[w][b_][8 + jj];
            gc += partials[w][b_][16 + jj];
            go += partials[w][b_][24 + jj];
        }
        gi += rb0; gf += rb1; gc += rb2; go += rb3;
        float si = 1.f / (1.f + __expf(-gi));
        float sf = 1.f / (1.f + __expf(-gf));
        float so = 1.f / (1.f + __expf(-go));
        float e2 = __expf(2.f * gc); float tc = (e2 - 1.f) / (e2 + 1.f);
        float c = sf * c_state + si * tc;
        c_state = c;
        float e2c = __expf(2.f * c); float th = (e2c - 1.f) / (e2c + 1.f);
        float h = so * th;
        unsigned short* hout = hbuf + ((t + 1) & 1) * (BB * HID);
        hout[b_ * HID + j0 + jj] = f2bf(h);
        if (t == TT - 1) hfinal[b_ * HID + j0 + jj] = h;
        __syncthreads();
        if (tid == 0)
            __hip_atomic_fetch_add(&arrive[t], 1u, __ATOMIC_RELEASE, __HIP_MEMORY_SCOPE_AGENT);
    }
}

// y[b][o] = dot(hfinal[b], Why[:,o]) + by[o]; one wave per output
__global__ void out_kernel(const float* __restrict__ hfinal, const float* __restrict__ Why,
                           const float* __restrict__ by, float* __restrict__ y) {
    int gw = blockIdx.x * 4 + (threadIdx.x >> 6);
    int lane = threadIdx.x & 63;
    int b = gw >> 1, o = gw & 1;
    float s = 0.f;
    for (int k = lane; k < HID; k += 64) s += hfinal[b * HID + k] * Why[k * 2 + o];
#pragma unroll
    for (int off = 32; off; off >>= 1) s += __shfl_down(s, off);
    if (lane == 0) y[b * 2 + o] = s + by[o];
}

extern "C" void kernel_launch(void* const* d_in, const int* in_sizes, int n_in,
                              void* d_out, int out_size, void* d_ws, size_t ws_size,
                              hipStream_t stream) {
    const int*   x   = (const int*)d_in[0];
    const float* emb = (const float*)d_in[1];
    const float* Wxi = (const float*)d_in[2];
    const float* Whi = (const float*)d_in[3];
    const float* bi  = (const float*)d_in[4];
    const float* Wxf = (const float*)d_in[5];
    const float* Whf = (const float*)d_in[6];
    const float* bfp = (const float*)d_in[7];
    const float* Wxc = (const float*)d_in[8];
    const float* Whc = (const float*)d_in[9];
    const float* bc  = (const float*)d_in[10];
    const float* Wxo = (const float*)d_in[11];
    const float* Who = (const float*)d_in[12];
    const float* bo  = (const float*)d_in[13];
    const float* Why = (const float*)d_in[14];
    const float* by  = (const float*)d_in[15];
    float* y = (float*)d_out;

    char* ws = (char*)d_ws;
    // layout: Wpack 12,582,912 | xe_all 33,554,432 | hbuf 262,144 | arrive 2,048 | hfinal 262,144
    unsigned short* Wpack  = (unsigned short*)ws;
    unsigned short* xe_all = (unsigned short*)(ws + 12582912);
    unsigned short* hbuf   = (unsigned short*)(ws + 12582912 + 33554432);
    unsigned*       arrive = (unsigned*)(ws + 12582912 + 33554432 + 262144);
    float*          hfinal = (float*)(ws + 12582912 + 33554432 + 262144 + 2048);

    // zero hbuf (65536 u32) + arrive (512 u32), contiguous
    zero_kernel<<<258, 256, 0, stream>>>((unsigned*)hbuf, 66048);
    wpack_kernel<<<3072, 256, 0, stream>>>(Wxi, Whi, Wxf, Whf, Wxc, Whc, Wxo, Who, Wpack);
    xe_kernel<<<32768, 128, 0, stream>>>(x, emb, xe_all);

    const unsigned short* xe_p = xe_all;
    const unsigned short* Wp_p = Wpack;
    unsigned short* hb_p = hbuf;
    float* hf_p = hfinal;
    unsigned* ar_p = arrive;
    void* args[] = {&xe_p, &Wp_p, &hb_p, &hf_p, &ar_p,
                    (void*)&bi, (void*)&bfp, (void*)&bc, (void*)&bo};
    hipLaunchCooperativeKernel((void*)lstm_kernel, dim3(NBLK), dim3(THREADS), args, 0, stream);

    out_kernel<<<32, 256, 0, stream>>>(hfinal, Why, by, y);
}

// Round 3
// 4027.881 us; speedup vs baseline: 3.0836x; 3.0836x over previous
//
#include <hip/hip_runtime.h>

#define TT 512
#define BB 64
#define EMB 512
#define HID 1024
#define K4 1536
#define NBLK 128
#define THREADS 512

typedef __bf16 bf16x8 __attribute__((ext_vector_type(8)));
typedef float f32x4 __attribute__((ext_vector_type(4)));

__device__ __forceinline__ unsigned short f2bf(float f) {
    union { float f; unsigned u; } v; v.f = f;
    unsigned u = v.u;
    unsigned r = u + 0x7FFFu + ((u >> 16) & 1u);
    return (unsigned short)(r >> 16);
}

__global__ void zero_kernel(unsigned* p, int n) {
    int i = blockIdx.x * 256 + threadIdx.x;
    if (i < n) p[i] = 0u;
}

// Gather embedding rows, cast to bf16: xe_all[t][b][0:512]
__global__ void xe_kernel(const int* __restrict__ x, const float* __restrict__ emb,
                          unsigned short* __restrict__ xe_all) {
    int rowid = blockIdx.x;            // t*64 + b
    int t = rowid >> 6, b = rowid & 63;
    int idx = x[b * TT + t];
    float4 v = ((const float4*)(emb + (long)idx * EMB))[threadIdx.x];
    ushort4 o;
    o.x = f2bf(v.x); o.y = f2bf(v.y); o.z = f2bf(v.z); o.w = f2bf(v.w);
    ((ushort4*)(xe_all + (long)rowid * EMB))[threadIdx.x] = o;
}

// Wpack[n][k] bf16, n in [0,4096): gate=n>>10, col=n&1023; k<512 from Wx_gate, else Wh_gate.
__global__ void wpack_kernel(const float* __restrict__ Wxi, const float* __restrict__ Whi,
                             const float* __restrict__ Wxf, const float* __restrict__ Whf,
                             const float* __restrict__ Wxc, const float* __restrict__ Whc,
                             const float* __restrict__ Wxo, const float* __restrict__ Who,
                             unsigned short* __restrict__ Wpack) {
    const float* Wx[4] = {Wxi, Wxf, Wxc, Wxo};
    const float* Wh[4] = {Whi, Whf, Whc, Who};
    int n0 = (blockIdx.x & 15) << 8;       // 0..3840 step 256
    int k0 = (blockIdx.x >> 4) << 3;       // 0..1528 step 8
    int g = n0 >> 10, col0 = n0 & 1023;
    const float* base = (k0 < 512) ? (Wx[g] + (long)k0 * HID + col0)
                                   : (Wh[g] + (long)(k0 - 512) * HID + col0);
    int tid = threadIdx.x;
    union { unsigned short s[8]; uint4 v; } out;
#pragma unroll
    for (int i = 0; i < 8; ++i) out.s[i] = f2bf(base[(long)i * HID + tid]);
    *(uint4*)(Wpack + (long)(n0 + tid) * K4 + k0) = out.v;
}

#define MFMA(a, b, c) __builtin_amdgcn_mfma_f32_16x16x32_bf16((a), (b), (c), 0, 0, 0)

__launch_bounds__(THREADS, 2)
__global__ void lstm_kernel(const unsigned short* __restrict__ xe_all,
                            const unsigned short* __restrict__ Wpack,
                            unsigned short* __restrict__ hbuf,   // [2][64][1024] bf16
                            float* __restrict__ hfinal,          // [64][1024] f32
                            unsigned* __restrict__ arrive,       // [512*16] (64B stride)
                            const float* __restrict__ bi_p, const float* __restrict__ bf_p,
                            const float* __restrict__ bc_p, const float* __restrict__ bo_p) {
    __shared__ unsigned short Wlds[32 * 1544];      // [c][k], pad 8 per row
    __shared__ float partials[4][64][34];           // [kslice][m][c]

    const int tid = threadIdx.x;
    const int wave = tid >> 6, lane = tid & 63;
    const int quad = lane >> 4, r16 = lane & 15;
    const int mt2 = wave & 1;          // m-half: rows mt2*32..+32
    const int ks4 = wave >> 1;         // k-slice
    const int j0 = blockIdx.x * 8;     // hidden slice [j0, j0+8)

    // ---- load W slice (32 gate-cols x 1536) into LDS, once ----
#pragma unroll
    for (int i = 0; i < 12; ++i) {
        int gidx = tid + i * THREADS;          // 0..6143
        int c = gidx / 192, q = gidx % 192;
        int n = ((c >> 3) << 10) + j0 + (c & 7);
        *(uint4*)(&Wlds[c * 1544 + q * 8]) = *(const uint4*)(Wpack + (long)n * K4 + q * 8);
    }
    const int b_ = tid >> 3, jj = tid & 7;
    float rb0 = bi_p[j0 + jj], rb1 = bf_p[j0 + jj], rb2 = bc_p[j0 + jj], rb3 = bo_p[j0 + jj];
    float c_state = 0.f;
    __syncthreads();

    const f32x4 zf = {0.f, 0.f, 0.f, 0.f};
    const int row0 = mt2 * 32 + r16;           // A rows row0 and row0+16

    for (int t = 0; t < TT; ++t) {
        const unsigned short* xe_t = xe_all + (long)t * (BB * EMB);
        const unsigned short* hb = hbuf + (t & 1) * (BB * HID);

        f32x4 acc00 = zf, acc01 = zf, acc10 = zf, acc11 = zf;

        // ---- Phase X: xe part (k < 512), no dependency on other blocks ----
        {
            uint4 xa[4][2];
#pragma unroll
            for (int i = 0; i < 4; ++i) {
                int k = ks4 * 128 + i * 32 + quad * 8;
                xa[i][0] = *(const uint4*)(xe_t + (long)row0 * EMB + k);
                xa[i][1] = *(const uint4*)(xe_t + (long)(row0 + 16) * EMB + k);
            }
#pragma unroll
            for (int i = 0; i < 4; ++i) {
                int k = ks4 * 128 + i * 32 + quad * 8;
                bf16x8 b0 = *(const bf16x8*)(&Wlds[r16 * 1544 + k]);
                bf16x8 b1 = *(const bf16x8*)(&Wlds[(16 + r16) * 1544 + k]);
                bf16x8 a0 = __builtin_bit_cast(bf16x8, xa[i][0]);
                bf16x8 a1 = __builtin_bit_cast(bf16x8, xa[i][1]);
                acc00 = MFMA(a0, b0, acc00); acc01 = MFMA(a0, b1, acc01);
                acc10 = MFMA(a1, b0, acc10); acc11 = MFMA(a1, b1, acc11);
            }
        }

        // ---- wait for h_t: single poller per block, broadcast via barrier ----
        if (t > 0 && tid == 0) {
            while (__hip_atomic_load(&arrive[(t - 1) * 16], __ATOMIC_RELAXED,
                                     __HIP_MEMORY_SCOPE_AGENT) < NBLK)
                __builtin_amdgcn_s_sleep(2);
        }
        __syncthreads();

        // ---- Phase H: h part (k >= 512), device-scope (LLC) loads, all in flight ----
        {
            uint4 ha[8][2];
#pragma unroll
            for (int i = 0; i < 8; ++i) {
                const unsigned short* p0 = hb + (long)row0 * HID + ks4 * 256 + i * 32 + quad * 8;
                const unsigned short* p1 = p0 + 16 * HID;
                asm volatile("global_load_dwordx4 %0, %1, off sc1" : "=v"(ha[i][0]) : "v"(p0));
                asm volatile("global_load_dwordx4 %0, %1, off sc1" : "=v"(ha[i][1]) : "v"(p1));
            }
            asm volatile("s_waitcnt vmcnt(0)" ::: "memory");
#pragma unroll
            for (int i = 0; i < 8; ++i) {
                int k = 512 + ks4 * 256 + i * 32 + quad * 8;
                bf16x8 b0 = *(const bf16x8*)(&Wlds[r16 * 1544 + k]);
                bf16x8 b1 = *(const bf16x8*)(&Wlds[(16 + r16) * 1544 + k]);
                bf16x8 a0 = __builtin_bit_cast(bf16x8, ha[i][0]);
                bf16x8 a1 = __builtin_bit_cast(bf16x8, ha[i][1]);
                acc00 = MFMA(a0, b0, acc00); acc01 = MFMA(a0, b1, acc01);
                acc10 = MFMA(a1, b0, acc10); acc11 = MFMA(a1, b1, acc11);
            }
        }

        // ---- partials (C layout: col=lane&15, row=(lane>>4)*4+reg) ----
        {
            int pr0 = mt2 * 32 + quad * 4;
#pragma unroll
            for (int rr = 0; rr < 4; ++rr) {
                partials[ks4][pr0 + rr][r16]           = acc00[rr];
                partials[ks4][pr0 + rr][16 + r16]      = acc01[rr];
                partials[ks4][pr0 + 16 + rr][r16]      = acc10[rr];
                partials[ks4][pr0 + 16 + rr][16 + r16] = acc11[rr];
            }
        }
        __syncthreads();

        // ---- elementwise: thread -> (b_, jj) ----
        float gi = 0.f, gf = 0.f, gc = 0.f, go = 0.f;
#pragma unroll
        for (int w = 0; w < 4; ++w) {
            gi += partials[w][b_][jj];
            gf += partials[w][b_][8 + jj];
            gc += partials[w][b_][16 + jj];
            go += partials[w][b_][24 + jj];
        }
        gi += rb0; gf += rb1; gc += rb2; go += rb3;
        float si = 1.f / (1.f + __expf(-gi));
        float sf = 1.f / (1.f + __expf(-gf));
        float so = 1.f / (1.f + __expf(-go));
        float e2 = __expf(2.f * gc); float tc = (e2 - 1.f) / (e2 + 1.f);
        float c = sf * c_state + si * tc;
        c_state = c;
        float e2c = __expf(2.f * c); float th = (e2c - 1.f) / (e2c + 1.f);
        float h = so * th;

        unsigned short hv = f2bf(h);
        const unsigned short* hop = hbuf + ((t + 1) & 1) * (BB * HID) + b_ * HID + j0 + jj;
        asm volatile("global_store_short %0, %1, off sc1" :: "v"(hop), "v"(hv) : "memory");
        if (t == TT - 1) hfinal[b_ * HID + j0 + jj] = h;
        asm volatile("s_waitcnt vmcnt(0)" ::: "memory");   // h at LLC before arrive
        __syncthreads();
        if (tid == 0)
            __hip_atomic_fetch_add(&arrive[t * 16], 1u, __ATOMIC_RELAXED,
                                   __HIP_MEMORY_SCOPE_AGENT);
    }
}

// y[b][o] = dot(hfinal[b], Why[:,o]) + by[o]; one wave per output
__global__ void out_kernel(const float* __restrict__ hfinal, const float* __restrict__ Why,
                           const float* __restrict__ by, float* __restrict__ y) {
    int gw = blockIdx.x * 4 + (threadIdx.x >> 6);
    int lane = threadIdx.x & 63;
    int b = gw >> 1, o = gw & 1;
    float s = 0.f;
    for (int k = lane; k < HID; k += 64) s += hfinal[b * HID + k] * Why[k * 2 + o];
#pragma unroll
    for (int off = 32; off; off >>= 1) s += __shfl_down(s, off);
    if (lane == 0) y[b * 2 + o] = s + by[o];
}

extern "C" void kernel_launch(void* const* d_in, const int* in_sizes, int n_in,
                              void* d_out, int out_size, void* d_ws, size_t ws_size,
                              hipStream_t stream) {
    const int*   x   = (const int*)d_in[0];
    const float* emb = (const float*)d_in[1];
    const float* Wxi = (const float*)d_in[2];
    const float* Whi = (const float*)d_in[3];
    const float* bi  = (const float*)d_in[4];
    const float* Wxf = (const float*)d_in[5];
    const float* Whf = (const float*)d_in[6];
    const float* bfp = (const float*)d_in[7];
    const float* Wxc = (const float*)d_in[8];
    const float* Whc = (const float*)d_in[9];
    const float* bc  = (const float*)d_in[10];
    const float* Wxo = (const float*)d_in[11];
    const float* Who = (const float*)d_in[12];
    const float* bo  = (const float*)d_in[13];
    const float* Why = (const float*)d_in[14];
    const float* by  = (const float*)d_in[15];
    float* y = (float*)d_out;

    char* ws = (char*)d_ws;
    // layout: Wpack 12,582,912 | xe_all 33,554,432 | hbuf 262,144 | arrive 32,768 | hfinal 262,144
    unsigned short* Wpack  = (unsigned short*)ws;
    unsigned short* xe_all = (unsigned short*)(ws + 12582912);
    unsigned short* hbuf   = (unsigned short*)(ws + 12582912 + 33554432);
    unsigned*       arrive = (unsigned*)(ws + 12582912 + 33554432 + 262144);
    float*          hfinal = (float*)(ws + 12582912 + 33554432 + 262144 + 32768);

    // zero hbuf (65536 u32) + arrive (8192 u32), contiguous
    zero_kernel<<<288, 256, 0, stream>>>((unsigned*)hbuf, 73728);
    wpack_kernel<<<3072, 256, 0, stream>>>(Wxi, Whi, Wxf, Whf, Wxc, Whc, Wxo, Who, Wpack);
    xe_kernel<<<32768, 128, 0, stream>>>(x, emb, xe_all);

    const unsigned short* xe_p = xe_all;
    const unsigned short* Wp_p = Wpack;
    unsigned short* hb_p = hbuf;
    float* hf_p = hfinal;
    unsigned* ar_p = arrive;
    void* args[] = {&xe_p, &Wp_p, &hb_p, &hf_p, &ar_p,
                    (void*)&bi, (void*)&bfp, (void*)&bc, (void*)&bo};
    hipLaunchCooperativeKernel((void*)lstm_kernel, dim3(NBLK), dim3(THREADS), args, 0, stream);

    out_kernel<<<32, 256, 0, stream>>>(hfinal, Why, by, y);
}

// Round 6
// 4004.687 us; speedup vs baseline: 3.1015x; 1.0058x over previous
//
#include <hip/hip_runtime.h>

#define TT 512
#define BB 64
#define EMB 512
#define HID 1024
#define K4 1536
#define NBLK 128
#define THREADS 512

typedef __bf16 bf16x8 __attribute__((ext_vector_type(8)));
typedef float f32x4 __attribute__((ext_vector_type(4)));

__device__ __forceinline__ unsigned short f2bf(float f) {
    union { float f; unsigned u; } v; v.f = f;
    unsigned u = v.u;
    unsigned r = u + 0x7FFFu + ((u >> 16) & 1u);
    return (unsigned short)(r >> 16);
}

__global__ void zero_kernel(unsigned* p, int n) {
    int i = blockIdx.x * 256 + threadIdx.x;
    if (i < n) p[i] = 0u;
}

// Gather embedding rows, cast to bf16: xe_all[t][b][0:512]
__global__ void xe_kernel(const int* __restrict__ x, const float* __restrict__ emb,
                          unsigned short* __restrict__ xe_all) {
    int rowid = blockIdx.x;            // t*64 + b
    int t = rowid >> 6, b = rowid & 63;
    int idx = x[b * TT + t];
    float4 v = ((const float4*)(emb + (long)idx * EMB))[threadIdx.x];
    ushort4 o;
    o.x = f2bf(v.x); o.y = f2bf(v.y); o.z = f2bf(v.z); o.w = f2bf(v.w);
    ((ushort4*)(xe_all + (long)rowid * EMB))[threadIdx.x] = o;
}

// Wpack[n][k] bf16, n in [0,4096): gate=n>>10, col=n&1023; k<512 from Wx_gate, else Wh_gate.
__global__ void wpack_kernel(const float* __restrict__ Wxi, const float* __restrict__ Whi,
                             const float* __restrict__ Wxf, const float* __restrict__ Whf,
                             const float* __restrict__ Wxc, const float* __restrict__ Whc,
                             const float* __restrict__ Wxo, const float* __restrict__ Who,
                             unsigned short* __restrict__ Wpack) {
    const float* Wx[4] = {Wxi, Wxf, Wxc, Wxo};
    const float* Wh[4] = {Whi, Whf, Whc, Who};
    int n0 = (blockIdx.x & 15) << 8;       // 0..3840 step 256
    int k0 = (blockIdx.x >> 4) << 3;       // 0..1528 step 8
    int g = n0 >> 10, col0 = n0 & 1023;
    const float* base = (k0 < 512) ? (Wx[g] + (long)k0 * HID + col0)
                                   : (Wh[g] + (long)(k0 - 512) * HID + col0);
    int tid = threadIdx.x;
    union { unsigned short s[8]; uint4 v; } out;
#pragma unroll
    for (int i = 0; i < 8; ++i) out.s[i] = f2bf(base[(long)i * HID + tid]);
    *(uint4*)(Wpack + (long)(n0 + tid) * K4 + k0) = out.v;
}

#define MFMA(a, b, c) __builtin_amdgcn_mfma_f32_16x16x32_bf16((a), (b), (c), 0, 0, 0)

__launch_bounds__(THREADS, 2)
__global__ void lstm_kernel(const unsigned short* __restrict__ xe_all,
                            const unsigned short* __restrict__ Wpack,
                            unsigned short* __restrict__ hbuf,   // [2][64][1024] bf16
                            float* __restrict__ hfinal,          // [64][1024] f32
                            unsigned* __restrict__ arrive,       // [512*8*16] (8 lines/step)
                            const float* __restrict__ bi_p, const float* __restrict__ bf_p,
                            const float* __restrict__ bc_p, const float* __restrict__ bo_p) {
    // W tile in LDS, XOR-swizzled at 16B-block granularity to spread banks:
    // chunk (c, bk) lives at block index c*192 + (bk ^ (c&7)); row stride 1536 (no pad).
    __shared__ unsigned short Wlds[32 * 1536];
    __shared__ float partials[4][64][34];           // [kslice][m][c]

    const int tid = threadIdx.x;
    const int wave = tid >> 6, lane = tid & 63;
    const int quad = lane >> 4, r16 = lane & 15;
    const int mt2 = wave & 1;          // m-half
    const int ks4 = wave >> 1;         // k-slice
    const int j0 = blockIdx.x * 8;     // hidden slice [j0, j0+8)

    // ---- load W slice (32 gate-cols x 1536) into LDS, once, swizzled ----
#pragma unroll
    for (int i = 0; i < 12; ++i) {
        int gidx = tid + i * THREADS;          // 0..6143
        int c = gidx / 192, q = gidx % 192;
        int n = ((c >> 3) << 10) + j0 + (c & 7);
        *(uint4*)(&Wlds[(c * 192 + (q ^ (c & 7))) * 8]) =
            *(const uint4*)(Wpack + (long)n * K4 + q * 8);
    }
    const int b_ = tid >> 3, jj = tid & 7;
    float rb0 = bi_p[j0 + jj], rb1 = bf_p[j0 + jj], rb2 = bc_p[j0 + jj], rb3 = bo_p[j0 + jj];
    float c_state = 0.f;
    __syncthreads();

    const f32x4 zf = {0.f, 0.f, 0.f, 0.f};
    const int row0 = mt2 * 32 + r16;           // A rows row0 and row0+16
    const int s0 = r16 & 7;                     // XOR key for B rows r16 and 16+r16

    for (int t = 0; t < TT; ++t) {
        const unsigned short* xe_t = xe_all + (long)t * (BB * EMB);
        const unsigned short* hb = hbuf + (t & 1) * (BB * HID);

        f32x4 acc00 = zf, acc01 = zf, acc10 = zf, acc11 = zf;

        // ---- Phase X: xe part (k < 512), no cross-block dependency ----
        {
            uint4 xa[4][2];
#pragma unroll
            for (int i = 0; i < 4; ++i) {
                int k = ks4 * 128 + i * 32 + quad * 8;
                xa[i][0] = *(const uint4*)(xe_t + (long)row0 * EMB + k);
                xa[i][1] = *(const uint4*)(xe_t + (long)(row0 + 16) * EMB + k);
            }
#pragma unroll
            for (int i = 0; i < 4; ++i) {
                int bk = (ks4 * 128 + i * 32 + quad * 8) >> 3;
                bf16x8 b0 = *(const bf16x8*)(&Wlds[(r16 * 192 + (bk ^ s0)) * 8]);
                bf16x8 b1 = *(const bf16x8*)(&Wlds[((16 + r16) * 192 + (bk ^ s0)) * 8]);
                bf16x8 a0 = __builtin_bit_cast(bf16x8, xa[i][0]);
                bf16x8 a1 = __builtin_bit_cast(bf16x8, xa[i][1]);
                acc00 = MFMA(a0, b0, acc00); acc01 = MFMA(a0, b1, acc01);
                acc10 = MFMA(a1, b0, acc10); acc11 = MFMA(a1, b1, acc11);
            }
        }

        // ---- wait for h_t: wave 0 polls the 8 sharded arrive lines ----
        if (t > 0 && wave == 0) {
            const unsigned* fp = &arrive[((t - 1) * 8 + (lane & 7)) * 16];
            while (!__all(__hip_atomic_load(fp, __ATOMIC_RELAXED,
                                            __HIP_MEMORY_SCOPE_AGENT) >= 16u))
                __builtin_amdgcn_s_sleep(2);
        }
        __syncthreads();

        // ---- Phase H: h part (k >= 512), device-scope (LLC) loads, all in flight ----
        {
            uint4 ha[8][2];
#pragma unroll
            for (int i = 0; i < 8; ++i) {
                const unsigned short* p0 = hb + (long)row0 * HID + ks4 * 256 + i * 32 + quad * 8;
                const unsigned short* p1 = p0 + 16 * HID;
                asm volatile("global_load_dwordx4 %0, %1, off sc1" : "=v"(ha[i][0]) : "v"(p0));
                asm volatile("global_load_dwordx4 %0, %1, off sc1" : "=v"(ha[i][1]) : "v"(p1));
            }
            asm volatile("s_waitcnt vmcnt(0)" ::: "memory");
#pragma unroll
            for (int i = 0; i < 8; ++i) {
                int bk = (512 + ks4 * 256 + i * 32 + quad * 8) >> 3;
                bf16x8 b0 = *(const bf16x8*)(&Wlds[(r16 * 192 + (bk ^ s0)) * 8]);
                bf16x8 b1 = *(const bf16x8*)(&Wlds[((16 + r16) * 192 + (bk ^ s0)) * 8]);
                bf16x8 a0 = __builtin_bit_cast(bf16x8, ha[i][0]);
                bf16x8 a1 = __builtin_bit_cast(bf16x8, ha[i][1]);
                acc00 = MFMA(a0, b0, acc00); acc01 = MFMA(a0, b1, acc01);
                acc10 = MFMA(a1, b0, acc10); acc11 = MFMA(a1, b1, acc11);
            }
        }

        // ---- partials (C layout: col=lane&15, row=(lane>>4)*4+reg) ----
        {
            int pr0 = mt2 * 32 + quad * 4;
#pragma unroll
            for (int rr = 0; rr < 4; ++rr) {
                partials[ks4][pr0 + rr][r16]           = acc00[rr];
                partials[ks4][pr0 + rr][16 + r16]      = acc01[rr];
                partials[ks4][pr0 + 16 + rr][r16]      = acc10[rr];
                partials[ks4][pr0 + 16 + rr][16 + r16] = acc11[rr];
            }
        }
        __syncthreads();

        // ---- elementwise: thread -> (b_, jj) ----
        float gi = 0.f, gf = 0.f, gc = 0.f, go = 0.f;
#pragma unroll
        for (int w = 0; w < 4; ++w) {
            gi += partials[w][b_][jj];
            gf += partials[w][b_][8 + jj];
            gc += partials[w][b_][16 + jj];
            go += partials[w][b_][24 + jj];
        }
        gi += rb0; gf += rb1; gc += rb2; go += rb3;
        float si = 1.f / (1.f + __expf(-gi));
        float sf = 1.f / (1.f + __expf(-gf));
        float so = 1.f / (1.f + __expf(-go));
        float e2 = __expf(2.f * gc); float tc = (e2 - 1.f) / (e2 + 1.f);
        float c = sf * c_state + si * tc;
        c_state = c;
        float e2c = __expf(2.f * c); float th = (e2c - 1.f) / (e2c + 1.f);
        float h = so * th;

        unsigned short hv = f2bf(h);
        const unsigned short* hop = hbuf + ((t + 1) & 1) * (BB * HID) + b_ * HID + j0 + jj;
        asm volatile("global_store_short %0, %1, off sc1" :: "v"(hop), "v"(hv) : "memory");
        if (t == TT - 1) hfinal[b_ * HID + j0 + jj] = h;
        asm volatile("s_waitcnt vmcnt(0)" ::: "memory");   // h at LLC before arrive
        __syncthreads();
        if (tid == 0)
            __hip_atomic_fetch_add(&arrive[(t * 8 + (blockIdx.x & 7)) * 16], 1u,
                                   __ATOMIC_RELAXED, __HIP_MEMORY_SCOPE_AGENT);
    }
}

// y[b][o] = dot(hfinal[b], Why[:,o]) + by[o]; one wave per output
__global__ void out_kernel(const float* __restrict__ hfinal, const float* __restrict__ Why,
                           const float* __restrict__ by, float* __restrict__ y) {
    int gw = blockIdx.x * 4 + (threadIdx.x >> 6);
    int lane = threadIdx.x & 63;
    int b = gw >> 1, o = gw & 1;
    float s = 0.f;
    for (int k = lane; k < HID; k += 64) s += hfinal[b * HID + k] * Why[k * 2 + o];
#pragma unroll
    for (int off = 32; off; off >>= 1) s += __shfl_down(s, off);
    if (lane == 0) y[b * 2 + o] = s + by[o];
}

extern "C" void kernel_launch(void* const* d_in, const int* in_sizes, int n_in,
                              void* d_out, int out_size, void* d_ws, size_t ws_size,
                              hipStream_t stream) {
    const int*   x   = (const int*)d_in[0];
    const float* emb = (const float*)d_in[1];
    const float* Wxi = (const float*)d_in[2];
    const float* Whi = (const float*)d_in[3];
    const float* bi  = (const float*)d_in[4];
    const float* Wxf = (const float*)d_in[5];
    const float* Whf = (const float*)d_in[6];
    const float* bfp = (const float*)d_in[7];
    const float* Wxc = (const float*)d_in[8];
    const float* Whc = (const float*)d_in[9];
    const float* bc  = (const float*)d_in[10];
    const float* Wxo = (const float*)d_in[11];
    const float* Who = (const float*)d_in[12];
    const float* bo  = (const float*)d_in[13];
    const float* Why = (const float*)d_in[14];
    const float* by  = (const float*)d_in[15];
    float* y = (float*)d_out;

    char* ws = (char*)d_ws;
    // layout: Wpack 12,582,912 | xe_all 33,554,432 | hbuf 262,144 | arrive 262,144 | hfinal 262,144
    unsigned short* Wpack  = (unsigned short*)ws;
    unsigned short* xe_all = (unsigned short*)(ws + 12582912);
    unsigned short* hbuf   = (unsigned short*)(ws + 12582912 + 33554432);
    unsigned*       arrive = (unsigned*)(ws + 12582912 + 33554432 + 262144);
    float*          hfinal = (float*)(ws + 12582912 + 33554432 + 262144 + 262144);

    // zero hbuf (65536 u32) + arrive (65536 u32), contiguous
    zero_kernel<<<512, 256, 0, stream>>>((unsigned*)hbuf, 131072);
    wpack_kernel<<<3072, 256, 0, stream>>>(Wxi, Whi, Wxf, Whf, Wxc, Whc, Wxo, Who, Wpack);
    xe_kernel<<<32768, 128, 0, stream>>>(x, emb, xe_all);

    const unsigned short* xe_p = xe_all;
    const unsigned short* Wp_p = Wpack;
    unsigned short* hb_p = hbuf;
    float* hf_p = hfinal;
    unsigned* ar_p = arrive;
    void* args[] = {&xe_p, &Wp_p, &hb_p, &hf_p, &ar_p,
                    (void*)&bi, (void*)&bfp, (void*)&bc, (void*)&bo};
    hipLaunchCooperativeKernel((void*)lstm_kernel, dim3(NBLK), dim3(THREADS), args, 0, stream);

    out_kernel<<<32, 256, 0, stream>>>(hfinal, Why, by, y);
}

// Round 7
// 2733.355 us; speedup vs baseline: 4.5441x; 1.4651x over previous
//
#include <hip/hip_runtime.h>

#define TT 512
#define BB 64
#define EMB 512
#define HID 1024
#define K4 1536
#define NBLK 256
#define THREADS 256

typedef __bf16 bf16x8 __attribute__((ext_vector_type(8)));
typedef float f32x4 __attribute__((ext_vector_type(4)));

__device__ __forceinline__ unsigned short f2bf(float f) {
    union { float f; unsigned u; } v; v.f = f;
    unsigned u = v.u;
    unsigned r = u + 0x7FFFu + ((u >> 16) & 1u);
    return (unsigned short)(r >> 16);
}

__global__ void zero_kernel(unsigned* p, int n) {
    int i = blockIdx.x * 256 + threadIdx.x;
    if (i < n) p[i] = 0u;
}

// Gather embedding rows, cast to bf16: xe_all[t][b][0:512]
__global__ void xe_kernel(const int* __restrict__ x, const float* __restrict__ emb,
                          unsigned short* __restrict__ xe_all) {
    int rowid = blockIdx.x;            // t*64 + b
    int t = rowid >> 6, b = rowid & 63;
    int idx = x[b * TT + t];
    float4 v = ((const float4*)(emb + (long)idx * EMB))[threadIdx.x];
    ushort4 o;
    o.x = f2bf(v.x); o.y = f2bf(v.y); o.z = f2bf(v.z); o.w = f2bf(v.w);
    ((ushort4*)(xe_all + (long)rowid * EMB))[threadIdx.x] = o;
}

// Wpack[n][k] bf16, n in [0,4096): gate=n>>10, col=n&1023; k<512 from Wx_gate, else Wh_gate.
__global__ void wpack_kernel(const float* __restrict__ Wxi, const float* __restrict__ Whi,
                             const float* __restrict__ Wxf, const float* __restrict__ Whf,
                             const float* __restrict__ Wxc, const float* __restrict__ Whc,
                             const float* __restrict__ Wxo, const float* __restrict__ Who,
                             unsigned short* __restrict__ Wpack) {
    const float* Wx[4] = {Wxi, Wxf, Wxc, Wxo};
    const float* Wh[4] = {Whi, Whf, Whc, Who};
    int n0 = (blockIdx.x & 15) << 8;       // 0..3840 step 256
    int k0 = (blockIdx.x >> 4) << 3;       // 0..1528 step 8
    int g = n0 >> 10, col0 = n0 & 1023;
    const float* base = (k0 < 512) ? (Wx[g] + (long)k0 * HID + col0)
                                   : (Wh[g] + (long)(k0 - 512) * HID + col0);
    int tid = threadIdx.x;
    union { unsigned short s[8]; uint4 v; } out;
#pragma unroll
    for (int i = 0; i < 8; ++i) out.s[i] = f2bf(base[(long)i * HID + tid]);
    *(uint4*)(Wpack + (long)(n0 + tid) * K4 + k0) = out.v;
}

#define MFMA(a, b, c) __builtin_amdgcn_mfma_f32_16x16x32_bf16((a), (b), (c), 0, 0, 0)

__launch_bounds__(THREADS, 1)
__global__ void lstm_kernel(const unsigned short* __restrict__ xe_all,
                            const unsigned short* __restrict__ Wpack,
                            unsigned short* __restrict__ hbuf,   // [2][64][1024] bf16
                            float* __restrict__ hfinal,          // [64][1024] f32
                            unsigned* __restrict__ arrive,       // [512*16*16] (16 lines/step)
                            const float* __restrict__ bi_p, const float* __restrict__ bf_p,
                            const float* __restrict__ bc_p, const float* __restrict__ bo_p) {
    // W tile in LDS, XOR-swizzled at 16B-block granularity (validated R6 layout):
    // chunk (c, bk) at block index c*192 + (bk ^ (c&7)); row stride 1536.
    __shared__ unsigned short Wlds[32 * 1536];
    __shared__ float partials[4][32][34];           // [kslice][m_local][c]

    const int tid = threadIdx.x;
    const int wave = tid >> 6, lane = tid & 63;
    const int quad = lane >> 4, r16 = lane & 15;
    const int ks4 = wave;              // k-slice (4 waves)
    const int bid = blockIdx.x;
    const int half = bid & 1;          // batch half: rows half*32..+32
    const int j0 = (bid >> 1) * 8;     // hidden slice [j0, j0+8)

    // ---- load W slice (32 gate-cols x 1536) into LDS, once, swizzled ----
#pragma unroll
    for (int i = 0; i < 24; ++i) {
        int gidx = tid + i * THREADS;          // 0..6143
        int c = gidx / 192, q = gidx % 192;
        int n = ((c >> 3) << 10) + j0 + (c & 7);
        *(uint4*)(&Wlds[(c * 192 + (q ^ (c & 7))) * 8]) =
            *(const uint4*)(Wpack + (long)n * K4 + q * 8);
    }
    const int b_loc = tid >> 3, jj = tid & 7;   // (local row, hidden col)
    const int b_ = half * 32 + b_loc;
    float rb0 = bi_p[j0 + jj], rb1 = bf_p[j0 + jj], rb2 = bc_p[j0 + jj], rb3 = bo_p[j0 + jj];
    float c_state = 0.f;
    __syncthreads();

    const f32x4 zf = {0.f, 0.f, 0.f, 0.f};
    const int row0 = half * 32 + r16;          // A rows row0 and row0+16
    const int s0 = r16 & 7;                    // XOR key for B rows r16 / 16+r16

    for (int t = 0; t < TT; ++t) {
        const unsigned short* xe_t = xe_all + (long)t * (BB * EMB);
        const unsigned short* hb = hbuf + (t & 1) * (BB * HID);

        f32x4 acc00 = zf, acc01 = zf, acc10 = zf, acc11 = zf;

        // ---- Phase X: xe part (k < 512), no cross-block dependency ----
        {
            uint4 xa[4][2];
#pragma unroll
            for (int i = 0; i < 4; ++i) {
                int k = ks4 * 128 + i * 32 + quad * 8;
                xa[i][0] = *(const uint4*)(xe_t + (long)row0 * EMB + k);
                xa[i][1] = *(const uint4*)(xe_t + (long)(row0 + 16) * EMB + k);
            }
#pragma unroll
            for (int i = 0; i < 4; ++i) {
                int bk = (ks4 * 128 + i * 32 + quad * 8) >> 3;
                bf16x8 b0 = *(const bf16x8*)(&Wlds[(r16 * 192 + (bk ^ s0)) * 8]);
                bf16x8 b1 = *(const bf16x8*)(&Wlds[((16 + r16) * 192 + (bk ^ s0)) * 8]);
                bf16x8 a0 = __builtin_bit_cast(bf16x8, xa[i][0]);
                bf16x8 a1 = __builtin_bit_cast(bf16x8, xa[i][1]);
                acc00 = MFMA(a0, b0, acc00); acc01 = MFMA(a0, b1, acc01);
                acc10 = MFMA(a1, b0, acc10); acc11 = MFMA(a1, b1, acc11);
            }
        }

        // ---- wait for h_t of OUR half: wave 0 polls the 8 sharded lines ----
        if (t > 0 && wave == 0) {
            const unsigned* fp = &arrive[((t - 1) * 16 + half * 8 + (lane & 7)) * 16];
            while (!__all(__hip_atomic_load(fp, __ATOMIC_RELAXED,
                                            __HIP_MEMORY_SCOPE_AGENT) >= 16u))
                __builtin_amdgcn_s_sleep(2);
        }
        __syncthreads();

        // ---- Phase H: h part (k >= 512), device-scope (LLC) loads, all in flight ----
        {
            uint4 ha[8][2];
#pragma unroll
            for (int i = 0; i < 8; ++i) {
                const unsigned short* p0 = hb + (long)row0 * HID + ks4 * 256 + i * 32 + quad * 8;
                const unsigned short* p1 = p0 + 16 * HID;
                asm volatile("global_load_dwordx4 %0, %1, off sc1" : "=v"(ha[i][0]) : "v"(p0));
                asm volatile("global_load_dwordx4 %0, %1, off sc1" : "=v"(ha[i][1]) : "v"(p1));
            }
            asm volatile("s_waitcnt vmcnt(0)" ::: "memory");
#pragma unroll
            for (int i = 0; i < 8; ++i) {
                int bk = (512 + ks4 * 256 + i * 32 + quad * 8) >> 3;
                bf16x8 b0 = *(const bf16x8*)(&Wlds[(r16 * 192 + (bk ^ s0)) * 8]);
                bf16x8 b1 = *(const bf16x8*)(&Wlds[((16 + r16) * 192 + (bk ^ s0)) * 8]);
                bf16x8 a0 = __builtin_bit_cast(bf16x8, ha[i][0]);
                bf16x8 a1 = __builtin_bit_cast(bf16x8, ha[i][1]);
                acc00 = MFMA(a0, b0, acc00); acc01 = MFMA(a0, b1, acc01);
                acc10 = MFMA(a1, b0, acc10); acc11 = MFMA(a1, b1, acc11);
            }
        }

        // ---- partials (C layout: col=lane&15, row=(lane>>4)*4+reg), m_local 0..31 ----
        {
            int pr0 = quad * 4;
#pragma unroll
            for (int rr = 0; rr < 4; ++rr) {
                partials[ks4][pr0 + rr][r16]           = acc00[rr];
                partials[ks4][pr0 + rr][16 + r16]      = acc01[rr];
                partials[ks4][pr0 + 16 + rr][r16]      = acc10[rr];
                partials[ks4][pr0 + 16 + rr][16 + r16] = acc11[rr];
            }
        }
        __syncthreads();

        // ---- elementwise: thread -> (b_loc, jj) ----
        float gi = 0.f, gf = 0.f, gc = 0.f, go = 0.f;
#pragma unroll
        for (int w = 0; w < 4; ++w) {
            gi += partials[w][b_loc][jj];
            gf += partials[w][b_loc][8 + jj];
            gc += partials[w][b_loc][16 + jj];
            go += partials[w][b_loc][24 + jj];
        }
        gi += rb0; gf += rb1; gc += rb2; go += rb3;
        float si = 1.f / (1.f + __expf(-gi));
        float sf = 1.f / (1.f + __expf(-gf));
        float so = 1.f / (1.f + __expf(-go));
        float e2 = __expf(2.f * gc); float tc = (e2 - 1.f) / (e2 + 1.f);
        float c = sf * c_state + si * tc;
        c_state = c;
        float e2c = __expf(2.f * c); float th = (e2c - 1.f) / (e2c + 1.f);
        float h = so * th;

        unsigned short hv = f2bf(h);
        const unsigned short* hop = hbuf + ((t + 1) & 1) * (BB * HID) + b_ * HID + j0 + jj;
        asm volatile("global_store_short %0, %1, off sc1" :: "v"(hop), "v"(hv) : "memory");
        if (t == TT - 1) hfinal[b_ * HID + j0 + jj] = h;
        asm volatile("s_waitcnt vmcnt(0)" ::: "memory");   // h at LLC before arrive
        __syncthreads();
        if (tid == 0)
            __hip_atomic_fetch_add(&arrive[(t * 16 + half * 8 + ((bid >> 1) & 7)) * 16], 1u,
                                   __ATOMIC_RELAXED, __HIP_MEMORY_SCOPE_AGENT);
    }
}

// y[b][o] = dot(hfinal[b], Why[:,o]) + by[o]; one wave per output
__global__ void out_kernel(const float* __restrict__ hfinal, const float* __restrict__ Why,
                           const float* __restrict__ by, float* __restrict__ y) {
    int gw = blockIdx.x * 4 + (threadIdx.x >> 6);
    int lane = threadIdx.x & 63;
    int b = gw >> 1, o = gw & 1;
    float s = 0.f;
    for (int k = lane; k < HID; k += 64) s += hfinal[b * HID + k] * Why[k * 2 + o];
#pragma unroll
    for (int off = 32; off; off >>= 1) s += __shfl_down(s, off);
    if (lane == 0) y[b * 2 + o] = s + by[o];
}

extern "C" void kernel_launch(void* const* d_in, const int* in_sizes, int n_in,
                              void* d_out, int out_size, void* d_ws, size_t ws_size,
                              hipStream_t stream) {
    const int*   x   = (const int*)d_in[0];
    const float* emb = (const float*)d_in[1];
    const float* Wxi = (const float*)d_in[2];
    const float* Whi = (const float*)d_in[3];
    const float* bi  = (const float*)d_in[4];
    const float* Wxf = (const float*)d_in[5];
    const float* Whf = (const float*)d_in[6];
    const float* bfp = (const float*)d_in[7];
    const float* Wxc = (const float*)d_in[8];
    const float* Whc = (const float*)d_in[9];
    const float* bc  = (const float*)d_in[10];
    const float* Wxo = (const float*)d_in[11];
    const float* Who = (const float*)d_in[12];
    const float* bo  = (const float*)d_in[13];
    const float* Why = (const float*)d_in[14];
    const float* by  = (const float*)d_in[15];
    float* y = (float*)d_out;

    char* ws = (char*)d_ws;
    // layout: Wpack 12,582,912 | xe_all 33,554,432 | hbuf 262,144 | arrive 524,288 | hfinal 262,144
    unsigned short* Wpack  = (unsigned short*)ws;
    unsigned short* xe_all = (unsigned short*)(ws + 12582912);
    unsigned short* hbuf   = (unsigned short*)(ws + 12582912 + 33554432);
    unsigned*       arrive = (unsigned*)(ws + 12582912 + 33554432 + 262144);
    float*          hfinal = (float*)(ws + 12582912 + 33554432 + 262144 + 524288);

    // zero hbuf (65536 u32) + arrive (131072 u32), contiguous
    zero_kernel<<<768, 256, 0, stream>>>((unsigned*)hbuf, 196608);
    wpack_kernel<<<3072, 256, 0, stream>>>(Wxi, Whi, Wxf, Whf, Wxc, Whc, Wxo, Who, Wpack);
    xe_kernel<<<32768, 128, 0, stream>>>(x, emb, xe_all);

    const unsigned short* xe_p = xe_all;
    const unsigned short* Wp_p = Wpack;
    unsigned short* hb_p = hbuf;
    float* hf_p = hfinal;
    unsigned* ar_p = arrive;
    void* args[] = {&xe_p, &Wp_p, &hb_p, &hf_p, &ar_p,
                    (void*)&bi, (void*)&bfp, (void*)&bc, (void*)&bo};
    hipLaunchCooperativeKernel((void*)lstm_kernel, dim3(NBLK), dim3(THREADS), args, 0, stream);

    out_kernel<<<32, 256, 0, stream>>>(hfinal, Why, by, y);
}